// Round 12
// baseline (120.928 us; speedup 1.0000x reference)
//
#include <hip/hip_runtime.h>
#include <math.h>

#define BB 16
#define NN 4096            // N == M == 4096
#define KK 128
#define RT 2048            // rows per block (8 per thread)
#define CT 64              // cols per block (one rotation group)
#define RPT 8              // rows per thread
#define TPB 256
#define NRTILE (NN / RT)   // 2
#define NCTILE (NN / CT)   // 64
#define W_POINT  1.0f
#define W_COEFF  0.5f
#define W_AFFINE 0.5f

typedef float f4 __attribute__((ext_vector_type(4)));

__device__ inline float min3f(float a, float b, float c) {
    float r;
    asm("v_min3_f32 %0, %1, %2, %3" : "=v"(r) : "v"(a), "v"(b), "v"(c));
    return r;
}

__device__ inline void compute_affine(const float* __restrict__ aff,
                                      float R[9], float sc[3], float tr[3]) {
    float ax = aff[0], ay = aff[1], az = aff[2];
    tr[0] = aff[3]; tr[1] = aff[4]; tr[2] = aff[5];
    sc[0] = aff[6]; sc[1] = aff[7]; sc[2] = aff[8];
    float cx = cosf(ax), sx = sinf(ax);
    float cy = cosf(ay), sy = sinf(ay);
    float cz = cosf(az), sz = sinf(az);
    R[0] = cy * cz;                 R[1] = -cy * sz;                R[2] = sy;
    R[3] = cx * sz + sx * sy * cz;  R[4] = cx * cz - sx * sy * sz;  R[5] = -sx * cy;
    R[6] = sx * sz - cx * sy * cz;  R[7] = sx * cz + cx * sy * sz;  R[8] = cx * cy;
}

__device__ inline void apply_affine(const float R[9], const float sc[3], const float tr[3],
                                    float x, float y, float z,
                                    float& ox, float& oy, float& oz) {
    ox = fmaf(fmaf(x, R[0], fmaf(y, R[3], z * R[6])), sc[0], tr[0]);
    oy = fmaf(fmaf(x, R[1], fmaf(y, R[4], z * R[7])), sc[1], tr[1]);
    oz = fmaf(fmaf(x, R[2], fmaf(y, R[5], z * R[8])), sc[2], tr[2]);
}

// One-pass Chamfer, scalar inner loop, minimal DS traffic.
// Block = 2048 rows x 64 cols of one batch's d2 tile (pair evaluated ONCE).
// grid = 16*2*64 = 2048 blocks -> 8 blocks/CU = 8 waves/SIMD (issue slots
// stay filled) while DS is only 2 ops/iter (1 ds_read_b128 of {x,y,z,w} +
// 1 ds_bpermute) -> LDS pipe ~14.5us/CU, well under the kernel time.
// pk-f32 is half-rate on gfx950, so scalar = same exec rate, fewer hazards.
// Row-mins thread-local; col-mins rotate one lane/iter. No atomics:
//   rp[(b*64+ctile)*NN + row]          row-partials (min over 64 later)
//   cp[((b*2+rtile)*4+wid)*NN + col]   per-wave col-partials (min over 8)
__global__ __launch_bounds__(TPB, 8) void chamfer_kernel(
        const float* __restrict__ pred_shape,
        const float* __restrict__ targ_shape,
        const float* __restrict__ targ_affine,
        float* __restrict__ rp,
        float* __restrict__ cp) {
    __shared__ float ldsb[CT * 4];   // slot s: {x, y, z, |t|^2} of col ctile*64+s

    const int bx    = blockIdx.x;
    const int ctile = bx & (NCTILE - 1);
    const int rtile = (bx >> 6) & (NRTILE - 1);
    const int b     = bx >> 7;
    const int tid   = threadIdx.x;
    const int lane  = tid & 63;
    const int wid   = tid >> 6;

    // ---- stage 64 transformed target cols ----
    if (tid < CT) {
        float R[9], sc[3], tr[3];
        compute_affine(targ_affine + b * 9, R, sc, tr);
        const float* t = targ_shape + ((size_t)b * NN + ctile * CT + tid) * 3;
        float mx, my, mz;
        apply_affine(R, sc, tr, t[0], t[1], t[2], mx, my, mz);
        ldsb[tid * 4 + 0] = mx;
        ldsb[tid * 4 + 1] = my;
        ldsb[tid * 4 + 2] = mz;
        ldsb[tid * 4 + 3] = fmaf(mx, mx, fmaf(my, my, mz * mz));
    }

    // ---- load 8 pred rows per thread ----
    const int rowbase = rtile * RT;
    float ax[RPT], ay[RPT], az[RPT], q2[RPT], rmin[RPT];
    #pragma unroll
    for (int k = 0; k < RPT; ++k) {
        const float* p = pred_shape + ((size_t)b * NN + rowbase + k * TPB + tid) * 3;
        float x = p[0], y = p[1], z = p[2];
        q2[k] = fmaf(x, x, fmaf(y, y, z * z));
        ax[k] = -2.0f * x; ay[k] = -2.0f * y; az[k] = -2.0f * z;
        rmin[k] = 1e30f;
    }
    __syncthreads();

    // ---- rotating scan: iter i, lane l handles col slot (l+i)&63 ----
    const f4* base = (const f4*)ldsb;
    float cr = 1e30f;                        // rotating col-min accumulator
    const int rot = ((lane + 1) & 63) << 2;
    int idx = lane;
    for (int i = 0; i < 64; ++i) {
        f4 t = base[idx];                    // one ds_read_b128
        float e[RPT];
        #pragma unroll
        for (int k = 0; k < RPT; ++k) {
            // ee = |t|^2 - 2 q.t   (3 fma; q2 deferred for row-min)
            float ee = fmaf(ax[k], t.x, fmaf(ay[k], t.y, fmaf(az[k], t.z, t.w)));
            rmin[k] = fminf(rmin[k], ee);
            e[k] = ee + q2[k];               // true d2 for col-min
        }
        // col-min over this lane's 8 rows, merged into rotating accumulator
        float t1 = min3f(e[0], e[1], e[2]);
        float t2 = min3f(e[3], e[4], e[5]);
        float t3 = min3f(e[6], e[7], cr);
        cr = min3f(t1, t2, t3);
        // rotate down one lane: new[l] = old[(l+1)&63]
        cr = __int_as_float(__builtin_amdgcn_ds_bpermute(rot, __float_as_int(cr)));
        idx = (idx + 1) & 63;
    }
    // after 64 iters + rotates, lane l holds col (ctile*64 + l)

    // ---- plain stores of owned partials (clamp commutes with min) ----
    #pragma unroll
    for (int k = 0; k < RPT; ++k)
        rp[((size_t)b * NCTILE + ctile) * NN + rowbase + k * TPB + tid] =
            fmaxf(q2[k] + rmin[k], 0.0f);
    cp[(((size_t)b * NRTILE + rtile) * 4 + wid) * NN + ctile * CT + lane] =
        fmaxf(cr, 0.0f);
}

// 512 blocks, all loads lane-coalesced.
// Blocks 0..255  (b = j>>4): rows. row = (j&15)*256+tid; min over 64 ctile
//   slabs rp[(b*64+c)*NN + row].
// Blocks 256..511: cols. col = (jj&15)*256+tid; min over 8 slices
//   cp[(b*8+s)*NN + col].
__global__ __launch_bounds__(TPB) void reduce_kernel(
        const float* __restrict__ rp, const float* __restrict__ cp,
        float* __restrict__ partials) {
    const int j   = blockIdx.x;
    const int tid = threadIdx.x;
    float m;
    if (j < 256) {
        const int b = j >> 4, row = (j & 15) * TPB + tid;
        const float* basep = rp + (size_t)b * NCTILE * NN + row;
        m = basep[0];
        #pragma unroll 8
        for (int c = 1; c < NCTILE; ++c) m = fminf(m, basep[(size_t)c * NN]);
    } else {
        const int jj = j - 256;
        const int b = jj >> 4, col = (jj & 15) * TPB + tid;
        const float* basep = cp + (size_t)b * 8 * NN + col;
        m = basep[0];
        #pragma unroll
        for (int s = 1; s < 8; ++s) m = fminf(m, basep[(size_t)s * NN]);
    }
    #pragma unroll
    for (int off = 32; off > 0; off >>= 1) m += __shfl_down(m, off);
    __shared__ float sps[4];
    if ((tid & 63) == 0) sps[tid >> 6] = m;
    __syncthreads();
    if (tid == 0) partials[j] = sps[0] + sps[1] + sps[2] + sps[3];
}

__global__ __launch_bounds__(TPB) void final_combine(
        const float* __restrict__ partials,
        const float* __restrict__ pred_w,  const float* __restrict__ targ_w,
        const float* __restrict__ pred_aff, const float* __restrict__ targ_aff,
        float* __restrict__ out) {
    const int tid = threadIdx.x;
    float ps = partials[tid] + partials[256 + tid];
    float cs = 0.0f;
    #pragma unroll
    for (int r = 0; r < (BB * KK) / TPB; ++r) {   // 2048 floats
        float d = pred_w[r * TPB + tid] - targ_w[r * TPB + tid];
        cs = fmaf(d, d, cs);
    }
    float as = 0.0f;
    if (tid < BB * 9) {
        float d = pred_aff[tid] - targ_aff[tid];
        as = d * d;
    }
    #pragma unroll
    for (int off = 32; off > 0; off >>= 1) {
        ps += __shfl_down(ps, off);
        cs += __shfl_down(cs, off);
        as += __shfl_down(as, off);
    }
    __shared__ float sps[4], scs[4], sas[4];
    const int wid = tid >> 6;
    if ((tid & 63) == 0) { sps[wid] = ps; scs[wid] = cs; sas[wid] = as; }
    __syncthreads();
    if (tid == 0) {
        float p = sps[0] + sps[1] + sps[2] + sps[3];
        float c = scs[0] + scs[1] + scs[2] + scs[3];
        float a = sas[0] + sas[1] + sas[2] + sas[3];
        float point  = p / (float)(BB * NN);   // row-min and col-min share denom
        float coeff  = c / (float)(BB * KK);
        float affine = a / (float)(BB * 9);
        out[0] = W_POINT * point + W_COEFF * coeff + W_AFFINE * affine;
        out[1] = point;
        out[2] = coeff;
        out[3] = affine;
    }
}

extern "C" void kernel_launch(void* const* d_in, const int* in_sizes, int n_in,
                              void* d_out, int out_size, void* d_ws, size_t ws_size,
                              hipStream_t stream) {
    const float* pred_shape = (const float*)d_in[0];
    const float* pred_w     = (const float*)d_in[1];
    const float* pred_aff   = (const float*)d_in[2];
    const float* targ_shape = (const float*)d_in[3];
    const float* targ_w     = (const float*)d_in[4];
    const float* targ_aff   = (const float*)d_in[5];
    float* out = (float*)d_out;

    // ws layout (all fully overwritten every call; no init needed):
    float* rp = (float*)d_ws;                              // 16*64*4096 = 16 MiB
    float* cp = rp + (size_t)BB * NCTILE * NN;             // 16*8*4096  = 2 MiB
    float* partials = cp + (size_t)BB * 8 * NN;            // 512 floats

    chamfer_kernel<<<dim3(BB * NRTILE * NCTILE), TPB, 0, stream>>>(
        pred_shape, targ_shape, targ_aff, rp, cp);
    reduce_kernel<<<512, TPB, 0, stream>>>(rp, cp, partials);
    final_combine<<<1, TPB, 0, stream>>>(partials, pred_w, targ_w,
                                         pred_aff, targ_aff, out);
}